// Round 1
// baseline (8365.558 us; speedup 1.0000x reference)
//
#include <hip/hip_runtime.h>
#include <hip/hip_bf16.h>

static constexpr int S = 64, T = 64, B = 64, E = 256, H = 256, V = 32000;
static constexpr int H4 = 4 * H;          // 1024
static constexpr int NCHUNK = 500;        // V / 64
static constexpr int NROW = (T - 1) * B;  // 4032

__device__ __forceinline__ float sigf(float x) { return 1.0f / (1.0f + __expf(-x)); }
__device__ __forceinline__ float tanhfast(float x) { return 1.0f - 2.0f / (__expf(2.0f * x) + 1.0f); }

// ---------------- f32 -> bf16 convert (Wcomb) ----------------
__global__ __launch_bounds__(256) void k_cvt_bf16(const float* __restrict__ src,
                                                  __hip_bfloat16* __restrict__ dst, int n) {
  int i = blockIdx.x * 256 + threadIdx.x;
  if (i < n) dst[i] = __float2bfloat16(src[i]);
}

// ---------------- encoder input GEMM: Xw[t][b][r] = emb(src)·Wih^T + bias -----
__global__ __launch_bounds__(256) void k_enc_input(
    const int* __restrict__ src, const float* __restrict__ emb,
    const float* __restrict__ WihF, const float* __restrict__ bF,
    const float* __restrict__ WihB, const float* __restrict__ bB,
    float* __restrict__ XwF, float* __restrict__ XwB) {
  int b = blockIdx.x, t = blockIdx.y, dir = blockIdx.z;
  int tid = threadIdx.x;
  __shared__ __align__(16) float x[E];
  int ts = dir == 0 ? t : (S - 1 - t);
  int row = src[ts * B + b];
  x[tid] = emb[row * E + tid];
  __syncthreads();
  const float* W = dir == 0 ? WihF : WihB;
  const float* bias = dir == 0 ? bF : bB;
  float* Xw = dir == 0 ? XwF : XwB;
  const float* w0 = W + (0 * H + tid) * E;
  const float* w1 = W + (1 * H + tid) * E;
  const float* w2 = W + (2 * H + tid) * E;
  const float* w3 = W + (3 * H + tid) * E;
  float a0 = 0, a1 = 0, a2 = 0, a3 = 0;
  for (int k = 0; k < E; k += 4) {
    float4 xv = *(const float4*)&x[k];
    float4 v0 = *(const float4*)&w0[k];
    float4 v1 = *(const float4*)&w1[k];
    float4 v2 = *(const float4*)&w2[k];
    float4 v3 = *(const float4*)&w3[k];
    a0 += xv.x * v0.x + xv.y * v0.y + xv.z * v0.z + xv.w * v0.w;
    a1 += xv.x * v1.x + xv.y * v1.y + xv.z * v1.z + xv.w * v1.w;
    a2 += xv.x * v2.x + xv.y * v2.y + xv.z * v2.z + xv.w * v2.w;
    a3 += xv.x * v3.x + xv.y * v3.y + xv.z * v3.z + xv.w * v3.w;
  }
  float* o = Xw + (t * B + b) * H4;
  o[0 * H + tid] = a0 + bias[0 * H + tid];
  o[1 * H + tid] = a1 + bias[1 * H + tid];
  o[2 * H + tid] = a2 + bias[2 * H + tid];
  o[3 * H + tid] = a3 + bias[3 * H + tid];
}

// ---------------- decoder input GEMM: YW[t][b][r] = emb(tgt[t])·WihY^T + db ---
__global__ __launch_bounds__(256) void k_dec_input(
    const int* __restrict__ tgt, const float* __restrict__ emb,
    const float* __restrict__ dWih, const float* __restrict__ db,
    float* __restrict__ YW) {
  int b = blockIdx.x, t = blockIdx.y;
  int tid = threadIdx.x;
  __shared__ __align__(16) float x[E];
  int row = tgt[t * B + b];
  x[tid] = emb[row * E + tid];
  __syncthreads();
  const float* w0 = dWih + (0 * H + tid) * 512;
  const float* w1 = dWih + (1 * H + tid) * 512;
  const float* w2 = dWih + (2 * H + tid) * 512;
  const float* w3 = dWih + (3 * H + tid) * 512;
  float a0 = 0, a1 = 0, a2 = 0, a3 = 0;
  for (int k = 0; k < E; k += 4) {
    float4 xv = *(const float4*)&x[k];
    float4 v0 = *(const float4*)&w0[k];
    float4 v1 = *(const float4*)&w1[k];
    float4 v2 = *(const float4*)&w2[k];
    float4 v3 = *(const float4*)&w3[k];
    a0 += xv.x * v0.x + xv.y * v0.y + xv.z * v0.z + xv.w * v0.w;
    a1 += xv.x * v1.x + xv.y * v1.y + xv.z * v1.z + xv.w * v1.w;
    a2 += xv.x * v2.x + xv.y * v2.y + xv.z * v2.z + xv.w * v2.w;
    a3 += xv.x * v3.x + xv.y * v3.y + xv.z * v3.z + xv.w * v3.w;
  }
  float* o = YW + (t * B + b) * H4;
  o[0 * H + tid] = a0 + db[0 * H + tid];
  o[1 * H + tid] = a1 + db[1 * H + tid];
  o[2 * H + tid] = a2 + db[2 * H + tid];
  o[3 * H + tid] = a3 + db[3 * H + tid];
}

// ---------------- one encoder timestep (both dirs in grid.y) ------------------
// grid (128, 2), block 256. Block owns 2 j's (all 4 gates), all 64 batch rows.
__global__ __launch_bounds__(256) void k_enc_step(
    int t, const float* __restrict__ XwF, const float* __restrict__ XwB,
    const float* __restrict__ WhhF, const float* __restrict__ WhhB,
    float* __restrict__ Hbuf, float* __restrict__ Cbuf,
    __hip_bfloat16* __restrict__ fwd_bf, __hip_bfloat16* __restrict__ bwd_bf) {
  int jsl = blockIdx.x, dir = blockIdx.y;
  int tid = threadIdx.x;
  int b = tid & 63, g = tid >> 6;
  int par = t & 1;
  const float* Hin = Hbuf + (par * 2 + dir) * (B * H);
  float* Hout = Hbuf + ((par ^ 1) * 2 + dir) * (B * H);
  __shared__ __align__(16) float h_lds[64 * 260];  // stride 260 (==4 mod 32)
  __shared__ float zz[64][4][2];
  for (int i = tid; i < B * H; i += 256) {
    int bb = i >> 8, k = i & 255;
    h_lds[bb * 260 + k] = Hin[i];
  }
  __syncthreads();
  const float* Whh = dir ? WhhB : WhhF;
  const float* Xw = dir ? XwB : XwF;
  int j0 = jsl * 2;
  const float* wr0 = Whh + (g * H + j0) * H;
  const float* wr1 = wr0 + H;
  const float* hrow = &h_lds[b * 260];
  float acc0 = 0, acc1 = 0;
  for (int k = 0; k < H; k += 4) {
    float4 xv = *(const float4*)&hrow[k];
    float4 v0 = *(const float4*)&wr0[k];
    float4 v1 = *(const float4*)&wr1[k];
    acc0 += xv.x * v0.x + xv.y * v0.y + xv.z * v0.z + xv.w * v0.w;
    acc1 += xv.x * v1.x + xv.y * v1.y + xv.z * v1.z + xv.w * v1.w;
  }
  const float* xwrow = Xw + (t * B + b) * H4;
  zz[b][g][0] = acc0 + xwrow[g * H + j0];
  zz[b][g][1] = acc1 + xwrow[g * H + j0 + 1];
  __syncthreads();
  if (tid < 128) {
    int bb = tid & 63, jj = (tid >> 6) & 1;
    int j = j0 + jj;
    float zi = zz[bb][0][jj], zf = zz[bb][1][jj], zg = zz[bb][2][jj], zo = zz[bb][3][jj];
    float* Cp = Cbuf + (dir * B + bb) * H + j;
    float c = sigf(zf) * (*Cp) + sigf(zi) * tanhfast(zg);
    *Cp = c;
    float h = sigf(zo) * tanhfast(c);
    Hout[bb * H + j] = h;
    __hip_bfloat16 hb = __float2bfloat16(h);
    if (dir == 0) fwd_bf[(t * B + bb) * H + j] = hb;
    else          bwd_bf[((S - 1 - t) * B + bb) * H + j] = hb;
  }
}

// ---------------- decoder init: dec_h = [hf|hb]Wh^T, dec_c = [cf|cb]Wc^T ------
__global__ __launch_bounds__(256) void k_dec_init(
    const float* __restrict__ Hbuf, const float* __restrict__ Cbuf,
    const float* __restrict__ Wh, const float* __restrict__ Wc,
    float* __restrict__ dechA, float* __restrict__ deccA) {
  int b = blockIdx.x, tid = threadIdx.x;
  __shared__ __align__(16) float ch[512], cc[512];
  // encoder final state lives at parity 0 (64 steps)
  ch[tid]       = Hbuf[(0 * 2 + 0) * (B * H) + b * H + tid];
  ch[256 + tid] = Hbuf[(0 * 2 + 1) * (B * H) + b * H + tid];
  cc[tid]       = Cbuf[(0 * B + b) * H + tid];
  cc[256 + tid] = Cbuf[(1 * B + b) * H + tid];
  __syncthreads();
  const float* wh = Wh + tid * 512;
  const float* wc = Wc + tid * 512;
  float ah = 0, ac = 0;
  for (int k = 0; k < 512; k += 4) {
    float4 hv = *(const float4*)&ch[k];
    float4 cv = *(const float4*)&cc[k];
    float4 w1 = *(const float4*)&wh[k];
    float4 w2 = *(const float4*)&wc[k];
    ah += hv.x * w1.x + hv.y * w1.y + hv.z * w1.z + hv.w * w1.w;
    ac += cv.x * w2.x + cv.y * w2.y + cv.z * w2.z + cv.w * w2.w;
  }
  dechA[b * H + tid] = ah;  // parity 0
  deccA[b * H + tid] = ac;
}

// ---------------- enc_proj[b][s][j] = enc_hiddens[b][s][:]·Watt[j][:] ---------
__global__ __launch_bounds__(256) void k_enc_proj(
    const __hip_bfloat16* __restrict__ fwd_bf, const __hip_bfloat16* __restrict__ bwd_bf,
    const float* __restrict__ Watt, __hip_bfloat16* __restrict__ encproj_bf) {
  int b = blockIdx.x, s = blockIdx.y, tid = threadIdx.x;
  __shared__ __align__(16) float eh[512];
  eh[tid]       = __bfloat162float(fwd_bf[(s * B + b) * H + tid]);
  eh[256 + tid] = __bfloat162float(bwd_bf[(s * B + b) * H + tid]);
  __syncthreads();
  const float* w = Watt + tid * 512;
  float acc = 0;
  for (int k = 0; k < 512; k += 4) {
    float4 xv = *(const float4*)&eh[k];
    float4 wv = *(const float4*)&w[k];
    acc += xv.x * wv.x + xv.y * wv.y + xv.z * wv.z + xv.w * wv.w;
  }
  encproj_bf[(b * S + s) * H + tid] = __float2bfloat16(acc);
}

// ---------------- decoder z + LSTM update. grid (128,2), block 256 ------------
__global__ __launch_bounds__(256) void k_dec_z(
    int t, const float* __restrict__ YW, const float* __restrict__ dWih,
    const float* __restrict__ dWhh, float* __restrict__ dechA,
    float* __restrict__ deccA, const float* __restrict__ Oprev) {
  int jp = blockIdx.x;  // 0..127 -> j pair
  int bh = blockIdx.y;  // batch half
  int tid = threadIdx.x;
  int b32 = tid & 31, g = (tid >> 5) & 3, jj = tid >> 7;
  int par = t & 1;
  const float* hin = dechA + par * (B * H);
  float* hout = dechA + (par ^ 1) * (B * H);
  const float* cin = deccA + par * (B * H);
  float* cout = deccA + (par ^ 1) * (B * H);
  __shared__ __align__(16) float x[32 * 516];  // [h(256)|o(256)] stride 516
  __shared__ float zz[32][4][2];
  for (int i = tid; i < 32 * 512; i += 256) {
    int bb = i >> 9, k = i & 511;
    int bg = bh * 32 + bb;
    x[bb * 516 + k] = (k < 256) ? hin[bg * H + k] : Oprev[bg * H + (k - 256)];
  }
  __syncthreads();
  int j = jp * 2 + jj;
  int r = g * H + j;
  const float* whh = dWhh + r * H;
  const float* wio = dWih + r * 512 + 256;
  const float* xr = &x[b32 * 516];
  float acc = 0;
  for (int k = 0; k < H; k += 4) {
    float4 hv = *(const float4*)&xr[k];
    float4 ov = *(const float4*)&xr[256 + k];
    float4 w1 = *(const float4*)&whh[k];
    float4 w2 = *(const float4*)&wio[k];
    acc += hv.x * w1.x + hv.y * w1.y + hv.z * w1.z + hv.w * w1.w;
    acc += ov.x * w2.x + ov.y * w2.y + ov.z * w2.z + ov.w * w2.w;
  }
  int bglob = bh * 32 + b32;
  acc += YW[(t * B + bglob) * H4 + r];
  zz[b32][g][jj] = acc;
  __syncthreads();
  if (tid < 64) {
    int bb = tid & 31, j2 = (tid >> 5) & 1;
    int bg = bh * 32 + bb, jg = jp * 2 + j2;
    float zi = zz[bb][0][j2], zf = zz[bb][1][j2], zg = zz[bb][2][j2], zo = zz[bb][3][j2];
    float c = sigf(zf) * cin[bg * H + jg] + sigf(zi) * tanhfast(zg);
    cout[bg * H + jg] = c;
    hout[bg * H + jg] = sigf(zo) * tanhfast(c);
  }
}

// ---------------- decoder attention + combine. grid (64,4), block 256 ---------
__global__ __launch_bounds__(256) void k_dec_attn(
    int t, const float* __restrict__ dechA, const __hip_bfloat16* __restrict__ encproj_bf,
    const __hip_bfloat16* __restrict__ fwd_bf, const __hip_bfloat16* __restrict__ bwd_bf,
    const __hip_bfloat16* __restrict__ wcomb_bf, float* __restrict__ outs,
    float* __restrict__ Oprev) {
  int b = blockIdx.x, jq = blockIdx.y, tid = threadIdx.x;
  int par = t & 1;
  const float* h = dechA + (par ^ 1) * (B * H) + b * H;
  __shared__ __align__(16) float hn[256];
  __shared__ float ep[64][4];
  __shared__ float alpha[64];
  __shared__ __align__(16) float av[512];
  __shared__ float op[64][4];
  hn[tid] = h[tid];
  __syncthreads();
  {  // e_t partials
    int s = tid >> 2, q = tid & 3;
    const __hip_bfloat16* pr = encproj_bf + (b * S + s) * H + q * 64;
    const float* hq = &hn[q * 64];
    float acc = 0;
    for (int k = 0; k < 64; k++) acc += __bfloat162float(pr[k]) * hq[k];
    ep[s][q] = acc;
  }
  __syncthreads();
  if (tid < 64) {  // softmax over s (single wave)
    float e = ep[tid][0] + ep[tid][1] + ep[tid][2] + ep[tid][3];
    float m = e;
    #pragma unroll
    for (int off = 32; off > 0; off >>= 1) m = fmaxf(m, __shfl_xor(m, off));
    float p = __expf(e - m);
    float ss = p;
    #pragma unroll
    for (int off = 32; off > 0; off >>= 1) ss += __shfl_xor(ss, off);
    alpha[tid] = p / ss;
  }
  __syncthreads();
  {  // a_t
    float a0 = 0, a1 = 0;
    for (int s = 0; s < 64; s++) {
      float al = alpha[s];
      a0 += al * __bfloat162float(fwd_bf[(s * B + b) * H + tid]);
      a1 += al * __bfloat162float(bwd_bf[(s * B + b) * H + tid]);
    }
    av[tid] = a0;
    av[256 + tid] = a1;
  }
  __syncthreads();
  {  // O = tanh([a|h]·Wcomb^T), this block covers j in [jq*64, jq*64+64)
    int jl = tid & 63, kq = tid >> 6;
    int j = jq * 64 + jl;
    const __hip_bfloat16* w = wcomb_bf + j * 768 + kq * 192;
    float acc = 0;
    for (int k = 0; k < 192; k++) {
      int kk = kq * 192 + k;
      float xv = (kk < 512) ? av[kk] : hn[kk - 512];
      acc += __bfloat162float(w[k]) * xv;
    }
    op[jl][kq] = acc;
  }
  __syncthreads();
  if (tid < 64) {
    int j = jq * 64 + tid;
    float o = tanhfast(op[tid][0] + op[tid][1] + op[tid][2] + op[tid][3]);
    outs[(t * B + b) * H + j] = o;
    Oprev[b * H + j] = o;
  }
}

// ---------------- vocab GEMM + chunk logsumexp partials + gold capture --------
// grid (500, 63), block 256 (16x16 thread tile, 4 rows x 4 vocab per thread)
__global__ __launch_bounds__(256) void k_vocab(
    const float* __restrict__ outs, const float* __restrict__ Wv,
    const int* __restrict__ tgt, float* __restrict__ part_max,
    float* __restrict__ part_sum, float* __restrict__ gold) {
  int vb = blockIdx.x, t = blockIdx.y, tid = threadIdx.x;
  int tx = tid & 15, ty = tid >> 4;
  __shared__ __align__(16) float ol[64 * 258];
  __shared__ float pm[64][4], ps[64][4];
  for (int i = tid; i < 64 * 256; i += 256) {
    int bb = i >> 8, k = i & 255;
    ol[bb * 258 + k] = outs[(t * B + bb) * H + k];
  }
  __syncthreads();
  float acc[4][4];
  #pragma unroll
  for (int i = 0; i < 4; i++)
    #pragma unroll
    for (int j = 0; j < 4; j++) acc[i][j] = 0.f;
  int v0 = vb * 64 + tx * 4;
  const float* w0 = Wv + (v0 + 0) * H;
  const float* w1 = Wv + (v0 + 1) * H;
  const float* w2 = Wv + (v0 + 2) * H;
  const float* w3 = Wv + (v0 + 3) * H;
  const float* a0 = &ol[(ty * 4 + 0) * 258];
  const float* a1 = &ol[(ty * 4 + 1) * 258];
  const float* a2 = &ol[(ty * 4 + 2) * 258];
  const float* a3 = &ol[(ty * 4 + 3) * 258];
  for (int k = 0; k < H; k += 4) {
    float4 r0 = *(const float4*)(a0 + k);
    float4 r1 = *(const float4*)(a1 + k);
    float4 r2 = *(const float4*)(a2 + k);
    float4 r3 = *(const float4*)(a3 + k);
    float4 q0 = *(const float4*)(w0 + k);
    float4 q1 = *(const float4*)(w1 + k);
    float4 q2 = *(const float4*)(w2 + k);
    float4 q3 = *(const float4*)(w3 + k);
    acc[0][0] += r0.x*q0.x + r0.y*q0.y + r0.z*q0.z + r0.w*q0.w;
    acc[0][1] += r0.x*q1.x + r0.y*q1.y + r0.z*q1.z + r0.w*q1.w;
    acc[0][2] += r0.x*q2.x + r0.y*q2.y + r0.z*q2.z + r0.w*q2.w;
    acc[0][3] += r0.x*q3.x + r0.y*q3.y + r0.z*q3.z + r0.w*q3.w;
    acc[1][0] += r1.x*q0.x + r1.y*q0.y + r1.z*q0.z + r1.w*q0.w;
    acc[1][1] += r1.x*q1.x + r1.y*q1.y + r1.z*q1.z + r1.w*q1.w;
    acc[1][2] += r1.x*q2.x + r1.y*q2.y + r1.z*q2.z + r1.w*q2.w;
    acc[1][3] += r1.x*q3.x + r1.y*q3.y + r1.z*q3.z + r1.w*q3.w;
    acc[2][0] += r2.x*q0.x + r2.y*q0.y + r2.z*q0.z + r2.w*q0.w;
    acc[2][1] += r2.x*q1.x + r2.y*q1.y + r2.z*q1.z + r2.w*q1.w;
    acc[2][2] += r2.x*q2.x + r2.y*q2.y + r2.z*q2.z + r2.w*q2.w;
    acc[2][3] += r2.x*q3.x + r2.y*q3.y + r2.z*q3.z + r2.w*q3.w;
    acc[3][0] += r3.x*q0.x + r3.y*q0.y + r3.z*q0.z + r3.w*q0.w;
    acc[3][1] += r3.x*q1.x + r3.y*q1.y + r3.z*q1.z + r3.w*q1.w;
    acc[3][2] += r3.x*q2.x + r3.y*q2.y + r3.z*q2.z + r3.w*q2.w;
    acc[3][3] += r3.x*q3.x + r3.y*q3.y + r3.z*q3.z + r3.w*q3.w;
  }
  __syncthreads();
  // reuse ol as logit tile [64][65]
  float* lt = ol;
  #pragma unroll
  for (int i = 0; i < 4; i++)
    #pragma unroll
    for (int j = 0; j < 4; j++) lt[(ty * 4 + i) * 65 + tx * 4 + j] = acc[i][j];
  __syncthreads();
  {
    int r = tid & 63, q = tid >> 6;
    const float* row = &lt[r * 65 + q * 16];
    float m = row[0];
    #pragma unroll
    for (int i = 1; i < 16; i++) m = fmaxf(m, row[i]);
    int g = tgt[(t + 1) * B + r];
    int grel = g - (vb * 64 + q * 16);
    float s = 0;
    for (int i = 0; i < 16; i++) {
      float val = row[i];
      s += __expf(val - m);
      if (i == grel) gold[t * B + r] = val;
    }
    pm[r][q] = m;
    ps[r][q] = s;
  }
  __syncthreads();
  if (tid < 64) {
    float M = fmaxf(fmaxf(pm[tid][0], pm[tid][1]), fmaxf(pm[tid][2], pm[tid][3]));
    float Ss = ps[tid][0] * __expf(pm[tid][0] - M) + ps[tid][1] * __expf(pm[tid][1] - M) +
               ps[tid][2] * __expf(pm[tid][2] - M) + ps[tid][3] * __expf(pm[tid][3] - M);
    int n = t * B + tid;
    part_max[n * NCHUNK + vb] = M;
    part_sum[n * NCHUNK + vb] = Ss;
  }
}

// ---------------- final: lse reduce + gold - lse, masked sum over t -----------
__global__ __launch_bounds__(256) void k_final(
    const float* __restrict__ part_max, const float* __restrict__ part_sum,
    const float* __restrict__ gold, const int* __restrict__ tgt,
    float* __restrict__ out) {
  int b = blockIdx.x, tid = threadIdx.x;
  int tq = tid >> 2, q = tid & 3;
  __shared__ float lm[64][4], ls[64][4];
  __shared__ float red[64];
  if (tq < T - 1) {
    int n = tq * B + b;
    float m = -__builtin_inff(), s = 0;
    for (int i = q; i < NCHUNK; i += 4) {
      float pmv = part_max[n * NCHUNK + i];
      float psv = part_sum[n * NCHUNK + i];
      float M2 = fmaxf(m, pmv);
      s = s * __expf(m - M2) + psv * __expf(pmv - M2);
      m = M2;
    }
    lm[tq][q] = m;
    ls[tq][q] = s;
  }
  __syncthreads();
  if (tid < T - 1) {
    float M = fmaxf(fmaxf(lm[tid][0], lm[tid][1]), fmaxf(lm[tid][2], lm[tid][3]));
    float Ss = ls[tid][0] * __expf(lm[tid][0] - M) + ls[tid][1] * __expf(lm[tid][1] - M) +
               ls[tid][2] * __expf(lm[tid][2] - M) + ls[tid][3] * __expf(lm[tid][3] - M);
    float lse = M + logf(Ss);
    int g = tgt[(tid + 1) * B + b];
    red[tid] = (g != 0) ? (gold[tid * B + b] - lse) : 0.f;
  }
  if (tid == T - 1) red[T - 1] = 0.f;
  __syncthreads();
  if (tid == 0) {
    float s = 0;
    for (int i = 0; i < T - 1; i++) s += red[i];
    out[b] = s;
  }
}

extern "C" void kernel_launch(void* const* d_in, const int* in_sizes, int n_in,
                              void* d_out, int out_size, void* d_ws, size_t ws_size,
                              hipStream_t stream) {
  (void)in_sizes; (void)n_in; (void)out_size; (void)ws_size;
  const int*   src   = (const int*)  d_in[0];
  const int*   tgt   = (const int*)  d_in[1];
  const float* semb  = (const float*)d_in[2];
  const float* temb  = (const float*)d_in[3];
  const float* WihF  = (const float*)d_in[4];
  const float* WhhF  = (const float*)d_in[5];
  const float* bF    = (const float*)d_in[6];
  const float* WihB  = (const float*)d_in[7];
  const float* WhhB  = (const float*)d_in[8];
  const float* bB    = (const float*)d_in[9];
  const float* dWih  = (const float*)d_in[10];
  const float* dWhh  = (const float*)d_in[11];
  const float* db    = (const float*)d_in[12];
  const float* Wh    = (const float*)d_in[13];
  const float* Wc    = (const float*)d_in[14];
  const float* Watt  = (const float*)d_in[15];
  const float* Wcomb = (const float*)d_in[16];
  const float* Wv    = (const float*)d_in[17];
  float* out = (float*)d_out;

  char* wp = (char*)d_ws;
  auto alloc = [&](size_t bytes) -> char* {
    char* p = wp;
    wp += (bytes + 255) & ~(size_t)255;
    return p;
  };
  float* XwF  = (float*)alloc((size_t)S * B * H4 * 4);
  float* XwB  = (float*)alloc((size_t)S * B * H4 * 4);
  float* YW   = (float*)alloc((size_t)(T - 1) * B * H4 * 4);
  float* outs = (float*)alloc((size_t)(T - 1) * B * H * 4);
  __hip_bfloat16* fwd_bf     = (__hip_bfloat16*)alloc((size_t)S * B * H * 2);
  __hip_bfloat16* bwd_bf     = (__hip_bfloat16*)alloc((size_t)S * B * H * 2);
  __hip_bfloat16* encproj_bf = (__hip_bfloat16*)alloc((size_t)B * S * H * 2);
  __hip_bfloat16* wcomb_bf   = (__hip_bfloat16*)alloc((size_t)H * 768 * 2);
  float* part_max = (float*)alloc((size_t)NROW * NCHUNK * 4);
  float* part_sum = (float*)alloc((size_t)NROW * NCHUNK * 4);
  float* gold     = (float*)alloc((size_t)NROW * 4);
  // state region (zero-initialized every call)
  char* stateBase = wp;
  float* Hbuf  = (float*)alloc((size_t)2 * 2 * B * H * 4);  // [parity][dir][b][j]
  float* Cbuf  = (float*)alloc((size_t)2 * B * H * 4);      // [dir][b][j]
  float* dechA = (float*)alloc((size_t)2 * B * H * 4);      // [parity][b][j]
  float* deccA = (float*)alloc((size_t)2 * B * H * 4);
  float* Oprev = (float*)alloc((size_t)B * H * 4);
  size_t stateBytes = (size_t)(wp - stateBase);
  hipMemsetAsync(stateBase, 0, stateBytes, stream);

  hipLaunchKernelGGL(k_cvt_bf16, dim3((H * 768 + 255) / 256), dim3(256), 0, stream,
                     Wcomb, wcomb_bf, H * 768);
  hipLaunchKernelGGL(k_enc_input, dim3(B, S, 2), dim3(256), 0, stream,
                     src, semb, WihF, bF, WihB, bB, XwF, XwB);
  hipLaunchKernelGGL(k_dec_input, dim3(B, T - 1), dim3(256), 0, stream,
                     tgt, temb, dWih, db, YW);
  for (int t = 0; t < S; t++) {
    hipLaunchKernelGGL(k_enc_step, dim3(128, 2), dim3(256), 0, stream,
                       t, XwF, XwB, WhhF, WhhB, Hbuf, Cbuf, fwd_bf, bwd_bf);
  }
  hipLaunchKernelGGL(k_dec_init, dim3(B), dim3(256), 0, stream,
                     Hbuf, Cbuf, Wh, Wc, dechA, deccA);
  hipLaunchKernelGGL(k_enc_proj, dim3(B, S), dim3(256), 0, stream,
                     fwd_bf, bwd_bf, Watt, encproj_bf);
  for (int t = 0; t < T - 1; t++) {
    hipLaunchKernelGGL(k_dec_z, dim3(128, 2), dim3(256), 0, stream,
                       t, YW, dWih, dWhh, dechA, deccA, Oprev);
    hipLaunchKernelGGL(k_dec_attn, dim3(B, 4), dim3(256), 0, stream,
                       t, dechA, encproj_bf, fwd_bf, bwd_bf, wcomb_bf, outs, Oprev);
  }
  hipLaunchKernelGGL(k_vocab, dim3(NCHUNK, T - 1), dim3(256), 0, stream,
                     outs, Wv, tgt, part_max, part_sum, gold);
  hipLaunchKernelGGL(k_final, dim3(B), dim3(256), 0, stream,
                     part_max, part_sum, gold, tgt, out);
}

// Round 2
// 2667.131 us; speedup vs baseline: 3.1365x; 3.1365x over previous
//
#include <hip/hip_runtime.h>
#include <hip/hip_bf16.h>

static constexpr int S = 64, T = 64, B = 64, E = 256, H = 256, V = 32000;
static constexpr int H4 = 4 * H;          // 1024
static constexpr int NCHUNK = 500;        // V / 64
static constexpr int NROW = (T - 1) * B;  // 4032
static constexpr int LDP = 264;           // LDS row stride (bf16 elems), 256+8 pad

typedef short bf16x8 __attribute__((ext_vector_type(8)));
typedef float f32x4 __attribute__((ext_vector_type(4)));

__device__ __forceinline__ float sigf(float x) { return 1.0f / (1.0f + __expf(-x)); }
__device__ __forceinline__ float tanhfast(float x) { return 1.0f - 2.0f / (__expf(2.0f * x) + 1.0f); }

// ---------------- f32 -> bf16 convert (flat) ----------------
__global__ __launch_bounds__(256) void k_cvt_bf16(const float* __restrict__ src,
                                                  __hip_bfloat16* __restrict__ dst, int n) {
  int i = blockIdx.x * 256 + threadIdx.x;
  if (i < n) dst[i] = __float2bfloat16(src[i]);
}

// ---------------- f32 [N][512] -> bf16 [N][256] (first-256 slice) -------------
__global__ __launch_bounds__(256) void k_cvt_slice(const float* __restrict__ src,
                                                   __hip_bfloat16* __restrict__ dst) {
  int n = blockIdx.x, tid = threadIdx.x;
  dst[n * 256 + tid] = __float2bfloat16(src[n * 512 + tid]);
}

// ---------------- embedding gather -> bf16 [rows][256] ------------------------
__global__ __launch_bounds__(256) void k_gather(const int* __restrict__ idx,
                                                const float* __restrict__ emb,
                                                __hip_bfloat16* __restrict__ dst) {
  int r = blockIdx.x, tid = threadIdx.x;
  dst[r * 256 + tid] = __float2bfloat16(emb[idx[r] * E + tid]);
}

// ============ shared MFMA 64x64 tile core (K=256, bf16 in, f32 acc) ===========
// Stages A rows [rb,rb+64) x 256 and W rows [cb,cb+64) x 256 into padded LDS,
// then 4 waves compute 32x32 quadrants. acc[m][n] is 2x2 fragments of 16x16.
#define MFMA_TILE_BODY(Abase, Wbase, rb, cb)                                     \
  const int tid = threadIdx.x;                                                   \
  const int lane = tid & 63, wid = tid >> 6;                                     \
  const int wr = wid >> 1, wc = wid & 1;                                         \
  const int l15 = lane & 15, l4 = lane >> 4;                                     \
  for (int it = 0; it < 8; it++) {                                               \
    int c = it * 256 + tid;                                                      \
    int row = c >> 5, off = (c & 31) * 8;                                        \
    *(uint4*)&Asl[row * LDP + off] =                                             \
        *(const uint4*)((Abase) + (size_t)((rb) + row) * 256 + off);             \
    *(uint4*)&Bsl[row * LDP + off] =                                             \
        *(const uint4*)((Wbase) + (size_t)((cb) + row) * 256 + off);             \
  }                                                                              \
  __syncthreads();                                                               \
  f32x4 acc[2][2];                                                               \
  for (int m = 0; m < 2; m++)                                                    \
    for (int n = 0; n < 2; n++) acc[m][n] = (f32x4){0.f, 0.f, 0.f, 0.f};         \
  for (int kk = 0; kk < 8; kk++) {                                               \
    int ko = kk * 32 + l4 * 8;                                                   \
    bf16x8 a0 = *(const bf16x8*)&Asl[(wr * 32 + l15) * LDP + ko];                \
    bf16x8 a1 = *(const bf16x8*)&Asl[(wr * 32 + 16 + l15) * LDP + ko];           \
    bf16x8 b0 = *(const bf16x8*)&Bsl[(wc * 32 + l15) * LDP + ko];                \
    bf16x8 b1 = *(const bf16x8*)&Bsl[(wc * 32 + 16 + l15) * LDP + ko];           \
    acc[0][0] = __builtin_amdgcn_mfma_f32_16x16x32_bf16(a0, b0, acc[0][0], 0, 0, 0); \
    acc[0][1] = __builtin_amdgcn_mfma_f32_16x16x32_bf16(a0, b1, acc[0][1], 0, 0, 0); \
    acc[1][0] = __builtin_amdgcn_mfma_f32_16x16x32_bf16(a1, b0, acc[1][0], 0, 0, 0); \
    acc[1][1] = __builtin_amdgcn_mfma_f32_16x16x32_bf16(a1, b1, acc[1][1], 0, 0, 0); \
  }

// ---------------- generic GEMM + bias: C[M][ldc] f32 = A x W^T + bias ---------
// grid (N/64, M/64), block 256
__global__ __launch_bounds__(256) void k_gemm_bias(
    const __hip_bfloat16* __restrict__ A, const __hip_bfloat16* __restrict__ W,
    const float* __restrict__ bias, float* __restrict__ C, int ldc) {
  __shared__ __align__(16) ushort Asl[64 * LDP];
  __shared__ __align__(16) ushort Bsl[64 * LDP];
  const int cb = blockIdx.x * 64, rb = blockIdx.y * 64;
  MFMA_TILE_BODY((const ushort*)A, (const ushort*)W, rb, cb)
  #pragma unroll
  for (int m = 0; m < 2; m++)
    #pragma unroll
    for (int n = 0; n < 2; n++) {
      int col = cb + wc * 32 + n * 16 + l15;
      float bv = bias[col];
      #pragma unroll
      for (int r = 0; r < 4; r++) {
        int row = rb + wr * 32 + m * 16 + l4 * 4 + r;
        C[(size_t)row * ldc + col] = acc[m][n][r] + bv;
      }
    }
}

// ---------------- vocab GEMM + fused chunk logsumexp + gold capture -----------
// grid (500, 63), block 256. rows tile == decoder step by (B==64).
__global__ __launch_bounds__(256) void k_vocab_mfma(
    const __hip_bfloat16* __restrict__ outs_bf, const __hip_bfloat16* __restrict__ Wv,
    const int* __restrict__ tgt, float* __restrict__ part_max,
    float* __restrict__ part_sum, float* __restrict__ gold) {
  __shared__ __align__(16) ushort Asl[64 * LDP];
  __shared__ __align__(16) ushort Bsl[64 * LDP];
  __shared__ int goldcol[64];
  __shared__ float pm[64][2], ps[64][2];
  const int vb = blockIdx.x, by = blockIdx.y;
  const int cb = vb * 64, rb = by * 64;
  if (threadIdx.x < 64) goldcol[threadIdx.x] = tgt[(by + 1) * B + threadIdx.x];
  MFMA_TILE_BODY((const ushort*)outs_bf, (const ushort*)Wv, rb, cb)
  // per-row (max, sumexp) over this block's 64 cols + gold capture
  #pragma unroll
  for (int m = 0; m < 2; m++) {
    #pragma unroll
    for (int r = 0; r < 4; r++) {
      int row_local = wr * 32 + m * 16 + l4 * 4 + r;
      // gold check (each lane: 2 cols per (m,r))
      int gc = goldcol[row_local];
      #pragma unroll
      for (int n = 0; n < 2; n++) {
        int col = cb + wc * 32 + n * 16 + l15;
        if (col == gc) gold[rb + row_local] = acc[m][n][r];
      }
      // wave-local row max over 32 cols (16 lanes x 2 n)
      float v = fmaxf(acc[m][0][r], acc[m][1][r]);
      #pragma unroll
      for (int o = 1; o < 16; o <<= 1) v = fmaxf(v, __shfl_xor(v, o));
      float e = __expf(acc[m][0][r] - v) + __expf(acc[m][1][r] - v);
      #pragma unroll
      for (int o = 1; o < 16; o <<= 1) e += __shfl_xor(e, o);
      if (l15 == 0) { pm[row_local][wc] = v; ps[row_local][wc] = e; }
    }
  }
  __syncthreads();
  if (tid < 64) {
    float m0 = pm[tid][0], m1 = pm[tid][1];
    float M = fmaxf(m0, m1);
    float Ss = ps[tid][0] * __expf(m0 - M) + ps[tid][1] * __expf(m1 - M);
    int n = rb + tid;
    part_max[(size_t)n * NCHUNK + vb] = M;
    part_sum[(size_t)n * NCHUNK + vb] = Ss;
  }
}

// ---------------- one encoder timestep (both dirs in grid.y) ------------------
__global__ __launch_bounds__(256) void k_enc_step(
    int t, const float* __restrict__ XwF, const float* __restrict__ XwB,
    const float* __restrict__ WhhF, const float* __restrict__ WhhB,
    float* __restrict__ Hbuf, float* __restrict__ Cbuf,
    __hip_bfloat16* __restrict__ fwd_bf, __hip_bfloat16* __restrict__ bwd_bf) {
  int jsl = blockIdx.x, dir = blockIdx.y;
  int tid = threadIdx.x;
  int b = tid & 63, g = tid >> 6;
  int par = t & 1;
  const float* Hin = Hbuf + (par * 2 + dir) * (B * H);
  float* Hout = Hbuf + ((par ^ 1) * 2 + dir) * (B * H);
  __shared__ __align__(16) float h_lds[64 * 260];
  __shared__ float zz[64][4][2];
  for (int i = tid; i < B * H; i += 256) {
    int bb = i >> 8, k = i & 255;
    h_lds[bb * 260 + k] = Hin[i];
  }
  __syncthreads();
  const float* Whh = dir ? WhhB : WhhF;
  const float* Xw = dir ? XwB : XwF;
  int ts = dir ? (S - 1 - t) : t;
  int j0 = jsl * 2;
  const float* wr0 = Whh + (g * H + j0) * H;
  const float* wr1 = wr0 + H;
  const float* hrow = &h_lds[b * 260];
  float acc0 = 0, acc1 = 0;
  for (int k = 0; k < H; k += 4) {
    float4 xv = *(const float4*)&hrow[k];
    float4 v0 = *(const float4*)&wr0[k];
    float4 v1 = *(const float4*)&wr1[k];
    acc0 += xv.x * v0.x + xv.y * v0.y + xv.z * v0.z + xv.w * v0.w;
    acc1 += xv.x * v1.x + xv.y * v1.y + xv.z * v1.z + xv.w * v1.w;
  }
  const float* xwrow = Xw + (ts * B + b) * H4;
  zz[b][g][0] = acc0 + xwrow[g * H + j0];
  zz[b][g][1] = acc1 + xwrow[g * H + j0 + 1];
  __syncthreads();
  if (tid < 128) {
    int bb = tid & 63, jj = (tid >> 6) & 1;
    int j = j0 + jj;
    float zi = zz[bb][0][jj], zf = zz[bb][1][jj], zg = zz[bb][2][jj], zo = zz[bb][3][jj];
    float* Cp = Cbuf + (dir * B + bb) * H + j;
    float c = sigf(zf) * (*Cp) + sigf(zi) * tanhfast(zg);
    *Cp = c;
    float h = sigf(zo) * tanhfast(c);
    Hout[bb * H + j] = h;
    __hip_bfloat16 hb = __float2bfloat16(h);
    if (dir == 0) fwd_bf[(t * B + bb) * H + j] = hb;
    else          bwd_bf[((S - 1 - t) * B + bb) * H + j] = hb;
  }
}

// ---------------- decoder init ------------------------------------------------
__global__ __launch_bounds__(256) void k_dec_init(
    const float* __restrict__ Hbuf, const float* __restrict__ Cbuf,
    const float* __restrict__ Wh, const float* __restrict__ Wc,
    float* __restrict__ dechA, float* __restrict__ deccA) {
  int b = blockIdx.x, tid = threadIdx.x;
  __shared__ __align__(16) float ch[512], cc[512];
  ch[tid]       = Hbuf[(0 * 2 + 0) * (B * H) + b * H + tid];
  ch[256 + tid] = Hbuf[(0 * 2 + 1) * (B * H) + b * H + tid];
  cc[tid]       = Cbuf[(0 * B + b) * H + tid];
  cc[256 + tid] = Cbuf[(1 * B + b) * H + tid];
  __syncthreads();
  const float* wh = Wh + tid * 512;
  const float* wc = Wc + tid * 512;
  float ah = 0, ac = 0;
  for (int k = 0; k < 512; k += 4) {
    float4 hv = *(const float4*)&ch[k];
    float4 cv = *(const float4*)&cc[k];
    float4 w1 = *(const float4*)&wh[k];
    float4 w2 = *(const float4*)&wc[k];
    ah += hv.x * w1.x + hv.y * w1.y + hv.z * w1.z + hv.w * w1.w;
    ac += cv.x * w2.x + cv.y * w2.y + cv.z * w2.z + cv.w * w2.w;
  }
  dechA[b * H + tid] = ah;
  deccA[b * H + tid] = ac;
}

// ---------------- enc_proj ----------------------------------------------------
__global__ __launch_bounds__(256) void k_enc_proj(
    const __hip_bfloat16* __restrict__ fwd_bf, const __hip_bfloat16* __restrict__ bwd_bf,
    const float* __restrict__ Watt, __hip_bfloat16* __restrict__ encproj_bf) {
  int b = blockIdx.x, s = blockIdx.y, tid = threadIdx.x;
  __shared__ __align__(16) float eh[512];
  eh[tid]       = __bfloat162float(fwd_bf[(s * B + b) * H + tid]);
  eh[256 + tid] = __bfloat162float(bwd_bf[(s * B + b) * H + tid]);
  __syncthreads();
  const float* w = Watt + tid * 512;
  float acc = 0;
  for (int k = 0; k < 512; k += 4) {
    float4 xv = *(const float4*)&eh[k];
    float4 wv = *(const float4*)&w[k];
    acc += xv.x * wv.x + xv.y * wv.y + xv.z * wv.z + xv.w * wv.w;
  }
  encproj_bf[(b * S + s) * H + tid] = __float2bfloat16(acc);
}

// ---------------- decoder z + LSTM update. grid (128,2), block 256 ------------
__global__ __launch_bounds__(256) void k_dec_z(
    int t, const float* __restrict__ YW, const float* __restrict__ dWih,
    const float* __restrict__ dWhh, float* __restrict__ dechA,
    float* __restrict__ deccA, const float* __restrict__ Oprev) {
  int jp = blockIdx.x;
  int bh = blockIdx.y;
  int tid = threadIdx.x;
  int b32 = tid & 31, g = (tid >> 5) & 3, jj = tid >> 7;
  int par = t & 1;
  const float* hin = dechA + par * (B * H);
  float* hout = dechA + (par ^ 1) * (B * H);
  const float* cin = deccA + par * (B * H);
  float* cout = deccA + (par ^ 1) * (B * H);
  __shared__ __align__(16) float x[32 * 516];
  __shared__ float zz[32][4][2];
  for (int i = tid; i < 32 * 512; i += 256) {
    int bb = i >> 9, k = i & 511;
    int bg = bh * 32 + bb;
    x[bb * 516 + k] = (k < 256) ? hin[bg * H + k] : Oprev[bg * H + (k - 256)];
  }
  __syncthreads();
  int j = jp * 2 + jj;
  int r = g * H + j;
  const float* whh = dWhh + r * H;
  const float* wio = dWih + r * 512 + 256;
  const float* xr = &x[b32 * 516];
  float acc = 0;
  for (int k = 0; k < H; k += 4) {
    float4 hv = *(const float4*)&xr[k];
    float4 ov = *(const float4*)&xr[256 + k];
    float4 w1 = *(const float4*)&whh[k];
    float4 w2 = *(const float4*)&wio[k];
    acc += hv.x * w1.x + hv.y * w1.y + hv.z * w1.z + hv.w * w1.w;
    acc += ov.x * w2.x + ov.y * w2.y + ov.z * w2.z + ov.w * w2.w;
  }
  int bglob = bh * 32 + b32;
  acc += YW[(t * B + bglob) * H4 + r];
  zz[b32][g][jj] = acc;
  __syncthreads();
  if (tid < 64) {
    int bb = tid & 31, j2 = (tid >> 5) & 1;
    int bg = bh * 32 + bb, jg = jp * 2 + j2;
    float zi = zz[bb][0][j2], zf = zz[bb][1][j2], zg = zz[bb][2][j2], zo = zz[bb][3][j2];
    float c = sigf(zf) * cin[bg * H + jg] + sigf(zi) * tanhfast(zg);
    cout[bg * H + jg] = c;
    hout[bg * H + jg] = sigf(zo) * tanhfast(c);
  }
}

// ---------------- decoder attention + combine. grid (64,4), block 256 ---------
__global__ __launch_bounds__(256) void k_dec_attn(
    int t, const float* __restrict__ dechA, const __hip_bfloat16* __restrict__ encproj_bf,
    const __hip_bfloat16* __restrict__ fwd_bf, const __hip_bfloat16* __restrict__ bwd_bf,
    const __hip_bfloat16* __restrict__ wcomb_bf, __hip_bfloat16* __restrict__ outs_bf,
    float* __restrict__ Oprev) {
  int b = blockIdx.x, jq = blockIdx.y, tid = threadIdx.x;
  int par = t & 1;
  const float* h = dechA + (par ^ 1) * (B * H) + b * H;
  __shared__ __align__(16) float hn[256];
  __shared__ float ep[64][4];
  __shared__ float alpha[64];
  __shared__ __align__(16) float av[512];
  __shared__ float op[64][4];
  hn[tid] = h[tid];
  __syncthreads();
  {
    int s = tid >> 2, q = tid & 3;
    const __hip_bfloat16* pr = encproj_bf + (b * S + s) * H + q * 64;
    const float* hq = &hn[q * 64];
    float acc = 0;
    for (int k = 0; k < 64; k++) acc += __bfloat162float(pr[k]) * hq[k];
    ep[s][q] = acc;
  }
  __syncthreads();
  if (tid < 64) {
    float e = ep[tid][0] + ep[tid][1] + ep[tid][2] + ep[tid][3];
    float m = e;
    #pragma unroll
    for (int off = 32; off > 0; off >>= 1) m = fmaxf(m, __shfl_xor(m, off));
    float p = __expf(e - m);
    float ss = p;
    #pragma unroll
    for (int off = 32; off > 0; off >>= 1) ss += __shfl_xor(ss, off);
    alpha[tid] = p / ss;
  }
  __syncthreads();
  {
    float a0 = 0, a1 = 0;
    for (int s = 0; s < 64; s++) {
      float al = alpha[s];
      a0 += al * __bfloat162float(fwd_bf[(s * B + b) * H + tid]);
      a1 += al * __bfloat162float(bwd_bf[(s * B + b) * H + tid]);
    }
    av[tid] = a0;
    av[256 + tid] = a1;
  }
  __syncthreads();
  {
    int jl = tid & 63, kq = tid >> 6;
    int j = jq * 64 + jl;
    const __hip_bfloat16* w = wcomb_bf + j * 768 + kq * 192;
    float acc = 0;
    for (int k = 0; k < 192; k++) {
      int kk = kq * 192 + k;
      float xv = (kk < 512) ? av[kk] : hn[kk - 512];
      acc += __bfloat162float(w[k]) * xv;
    }
    op[jl][kq] = acc;
  }
  __syncthreads();
  if (tid < 64) {
    int j = jq * 64 + tid;
    float o = tanhfast(op[tid][0] + op[tid][1] + op[tid][2] + op[tid][3]);
    outs_bf[(t * B + b) * H + j] = __float2bfloat16(o);
    Oprev[b * H + j] = o;
  }
}

// ---------------- final reduce ------------------------------------------------
__global__ __launch_bounds__(256) void k_final(
    const float* __restrict__ part_max, const float* __restrict__ part_sum,
    const float* __restrict__ gold, const int* __restrict__ tgt,
    float* __restrict__ out) {
  int b = blockIdx.x, tid = threadIdx.x;
  int tq = tid >> 2, q = tid & 3;
  __shared__ float lm[64][4], ls[64][4];
  __shared__ float red[64];
  if (tq < T - 1) {
    int n = tq * B + b;
    float m = -__builtin_inff(), s = 0;
    for (int i = q; i < NCHUNK; i += 4) {
      float pmv = part_max[(size_t)n * NCHUNK + i];
      float psv = part_sum[(size_t)n * NCHUNK + i];
      float M2 = fmaxf(m, pmv);
      s = s * __expf(m - M2) + psv * __expf(pmv - M2);
      m = M2;
    }
    lm[tq][q] = m;
    ls[tq][q] = s;
  }
  __syncthreads();
  if (tid < T - 1) {
    float M = fmaxf(fmaxf(lm[tid][0], lm[tid][1]), fmaxf(lm[tid][2], lm[tid][3]));
    float Ss = ls[tid][0] * __expf(lm[tid][0] - M) + ls[tid][1] * __expf(lm[tid][1] - M) +
               ls[tid][2] * __expf(lm[tid][2] - M) + ls[tid][3] * __expf(lm[tid][3] - M);
    float lse = M + logf(Ss);
    int g = tgt[(tid + 1) * B + b];
    red[tid] = (g != 0) ? (gold[tid * B + b] - lse) : 0.f;
  }
  if (tid == T - 1) red[T - 1] = 0.f;
  __syncthreads();
  if (tid == 0) {
    float s = 0;
    for (int i = 0; i < T - 1; i++) s += red[i];
    out[b] = s;
  }
}

extern "C" void kernel_launch(void* const* d_in, const int* in_sizes, int n_in,
                              void* d_out, int out_size, void* d_ws, size_t ws_size,
                              hipStream_t stream) {
  (void)in_sizes; (void)n_in; (void)out_size; (void)ws_size;
  const int*   src   = (const int*)  d_in[0];
  const int*   tgt   = (const int*)  d_in[1];
  const float* semb  = (const float*)d_in[2];
  const float* temb  = (const float*)d_in[3];
  const float* WihF  = (const float*)d_in[4];
  const float* WhhF  = (const float*)d_in[5];
  const float* bF    = (const float*)d_in[6];
  const float* WihB  = (const float*)d_in[7];
  const float* WhhB  = (const float*)d_in[8];
  const float* bB    = (const float*)d_in[9];
  const float* dWih  = (const float*)d_in[10];
  const float* dWhh  = (const float*)d_in[11];
  const float* db    = (const float*)d_in[12];
  const float* Wh    = (const float*)d_in[13];
  const float* Wc    = (const float*)d_in[14];
  const float* Watt  = (const float*)d_in[15];
  const float* Wcomb = (const float*)d_in[16];
  const float* Wv    = (const float*)d_in[17];
  float* out = (float*)d_out;

  char* wp = (char*)d_ws;
  auto alloc = [&](size_t bytes) -> char* {
    char* p = wp;
    wp += (bytes + 255) & ~(size_t)255;
    return p;
  };
  float* XwF  = (float*)alloc((size_t)S * B * H4 * 4);
  float* XwB  = (float*)alloc((size_t)S * B * H4 * 4);
  float* YW   = (float*)alloc((size_t)(T - 1) * B * H4 * 4);
  __hip_bfloat16* fwd_bf     = (__hip_bfloat16*)alloc((size_t)S * B * H * 2);
  __hip_bfloat16* bwd_bf     = (__hip_bfloat16*)alloc((size_t)S * B * H * 2);
  __hip_bfloat16* encproj_bf = (__hip_bfloat16*)alloc((size_t)B * S * H * 2);
  __hip_bfloat16* wcomb_bf   = (__hip_bfloat16*)alloc((size_t)H * 768 * 2);
  __hip_bfloat16* Ag         = (__hip_bfloat16*)alloc((size_t)S * B * E * 2);
  __hip_bfloat16* Yg         = (__hip_bfloat16*)alloc((size_t)(T - 1) * B * E * 2);
  __hip_bfloat16* WihF_bf    = (__hip_bfloat16*)alloc((size_t)H4 * E * 2);
  __hip_bfloat16* WihB_bf    = (__hip_bfloat16*)alloc((size_t)H4 * E * 2);
  __hip_bfloat16* dWih_bf    = (__hip_bfloat16*)alloc((size_t)H4 * E * 2);
  __hip_bfloat16* Wv_bf      = (__hip_bfloat16*)alloc((size_t)V * H * 2);
  __hip_bfloat16* outs_bf    = (__hip_bfloat16*)alloc((size_t)NROW * H * 2);
  float* part_max = (float*)alloc((size_t)NROW * NCHUNK * 4);
  float* part_sum = (float*)alloc((size_t)NROW * NCHUNK * 4);
  float* gold     = (float*)alloc((size_t)NROW * 4);
  // state region (zero-initialized every call)
  char* stateBase = wp;
  float* Hbuf  = (float*)alloc((size_t)2 * 2 * B * H * 4);
  float* Cbuf  = (float*)alloc((size_t)2 * B * H * 4);
  float* dechA = (float*)alloc((size_t)2 * B * H * 4);
  float* deccA = (float*)alloc((size_t)2 * B * H * 4);
  float* Oprev = (float*)alloc((size_t)B * H * 4);
  size_t stateBytes = (size_t)(wp - stateBase);
  hipMemsetAsync(stateBase, 0, stateBytes, stream);

  // converts + gathers
  hipLaunchKernelGGL(k_cvt_bf16, dim3((H * 768 + 255) / 256), dim3(256), 0, stream,
                     Wcomb, wcomb_bf, H * 768);
  hipLaunchKernelGGL(k_cvt_bf16, dim3((H4 * E + 255) / 256), dim3(256), 0, stream,
                     WihF, WihF_bf, H4 * E);
  hipLaunchKernelGGL(k_cvt_bf16, dim3((H4 * E + 255) / 256), dim3(256), 0, stream,
                     WihB, WihB_bf, H4 * E);
  hipLaunchKernelGGL(k_cvt_slice, dim3(H4), dim3(256), 0, stream, dWih, dWih_bf);
  hipLaunchKernelGGL(k_cvt_bf16, dim3((V * H + 255) / 256), dim3(256), 0, stream,
                     Wv, Wv_bf, V * H);
  hipLaunchKernelGGL(k_gather, dim3(S * B), dim3(256), 0, stream, src, semb, Ag);
  hipLaunchKernelGGL(k_gather, dim3((T - 1) * B), dim3(256), 0, stream, tgt, temb, Yg);

  // input GEMMs (MFMA)
  hipLaunchKernelGGL(k_gemm_bias, dim3(H4 / 64, S * B / 64), dim3(256), 0, stream,
                     Ag, WihF_bf, bF, XwF, H4);
  hipLaunchKernelGGL(k_gemm_bias, dim3(H4 / 64, S * B / 64), dim3(256), 0, stream,
                     Ag, WihB_bf, bB, XwB, H4);
  hipLaunchKernelGGL(k_gemm_bias, dim3(H4 / 64, (T - 1) * B / 64), dim3(256), 0, stream,
                     Yg, dWih_bf, db, YW, H4);

  for (int t = 0; t < S; t++) {
    hipLaunchKernelGGL(k_enc_step, dim3(128, 2), dim3(256), 0, stream,
                       t, XwF, XwB, WhhF, WhhB, Hbuf, Cbuf, fwd_bf, bwd_bf);
  }
  hipLaunchKernelGGL(k_dec_init, dim3(B), dim3(256), 0, stream,
                     Hbuf, Cbuf, Wh, Wc, dechA, deccA);
  hipLaunchKernelGGL(k_enc_proj, dim3(B, S), dim3(256), 0, stream,
                     fwd_bf, bwd_bf, Watt, encproj_bf);
  for (int t = 0; t < T - 1; t++) {
    hipLaunchKernelGGL(k_dec_z, dim3(128, 2), dim3(256), 0, stream,
                       t, YW, dWih, dWhh, dechA, deccA, Oprev);
    hipLaunchKernelGGL(k_dec_attn, dim3(B, 4), dim3(256), 0, stream,
                       t, dechA, encproj_bf, fwd_bf, bwd_bf, wcomb_bf, outs_bf, Oprev);
  }
  hipLaunchKernelGGL(k_vocab_mfma, dim3(NCHUNK, T - 1), dim3(256), 0, stream,
                     outs_bf, Wv_bf, tgt, part_max, part_sum, gold);
  hipLaunchKernelGGL(k_final, dim3(B), dim3(256), 0, stream,
                     part_max, part_sum, gold, tgt, out);
}